// Round 4
// 2056.400 us; speedup vs baseline: 1.1600x; 1.1600x over previous
//
#include <hip/hip_runtime.h>

// LSTM: I=H=1024, B=64, S=512.
//   pack_wT:    transpose+convert 8 weight mats -> WiT[4096][1024], WhT[4096][1024] bf16
//   pack_misc:  bias[4096] = b_i*+b_h*; zero h ping-pong buffers + flags
//   gemm_xproj: x_proj bf16, gate-interleaved layout [b][t][h][gate]
//   lstm_scan:  persistent, 256 blocks (one per CU), 512 steps.
//               R8: risk-isolated increment over the PROVEN R4/R0 kernel
//               (no new construct types after three unbenchable rounds):
//               - 8 groups x 8 batch rows (was 4x16): staging 32KB->16KB/WG,
//                 producer set 64->32 flags. Same flag/ping-pong protocol.
//               - 2 independent MFMA accumulator chains per wave (2 N-tiles
//                 of 16 cols): halves the exposed dependent-MFMA latency.
//               - __launch_bounds__(256,1): B-fragments (2x128 regs) stay
//                 register/AGPR-resident; grid=256 is 1 WG/CU anyway.
//               All sync, atomics, staging asm identical to the benched R0.
// Workspace: 285,493,248 B (guarded).

typedef __bf16 bf16x8 __attribute__((ext_vector_type(8)));
typedef float f32x4 __attribute__((ext_vector_type(4)));
typedef unsigned int uint4v __attribute__((ext_vector_type(4)));

__device__ __forceinline__ unsigned short f2bf(float f) {
    unsigned int u = __float_as_uint(f);
    u = (u + 0x7FFFu + ((u >> 16) & 1u)) >> 16;
    return (unsigned short)u;
}
__device__ __forceinline__ float bf2f(unsigned short u) {
    return __uint_as_float((unsigned int)u << 16);
}

// ---------------------------------------------------------------------------
// Pack weights: out[n][k] = w[k][n&1023] for gate n>>10, bf16. 64x64 LDS transpose.
__global__ __launch_bounds__(256) void pack_wT(
    const float* __restrict__ w0, const float* __restrict__ w1,
    const float* __restrict__ w2, const float* __restrict__ w3,
    const float* __restrict__ w4, const float* __restrict__ w5,
    const float* __restrict__ w6, const float* __restrict__ w7,
    unsigned short* __restrict__ wiT, unsigned short* __restrict__ whT)
{
    __shared__ float tl[64][65];
    int bid = blockIdx.x;
    int mi = bid >> 8;          // 0..7: 0..3 = Wi gates i,f,g,o; 4..7 = Wh
    int tile = bid & 255;
    int tk = tile >> 4, tj = tile & 15;
    const float* w;
    int gate = mi & 3;
    if (mi < 4) w = (gate == 0) ? w0 : (gate == 1) ? w1 : (gate == 2) ? w2 : w3;
    else        w = (gate == 0) ? w4 : (gate == 1) ? w5 : (gate == 2) ? w6 : w7;
    unsigned short* out = (mi < 4) ? wiT : whT;
    int tx = threadIdx.x & 63, ty = threadIdx.x >> 6;
    #pragma unroll
    for (int i = 0; i < 16; i++) {
        int k = i * 4 + ty;
        tl[k][tx] = w[(long)(tk * 64 + k) * 1024 + tj * 64 + tx];
    }
    __syncthreads();
    #pragma unroll
    for (int i = 0; i < 16; i++) {
        int j = i * 4 + ty;
        out[(long)(gate * 1024 + tj * 64 + j) * 1024 + tk * 64 + tx] = f2bf(tl[tx][j]);
    }
}

// ---------------------------------------------------------------------------
__global__ __launch_bounds__(256) void pack_misc(
    const float* __restrict__ bi0, const float* __restrict__ bh0,
    const float* __restrict__ bi1, const float* __restrict__ bh1,
    const float* __restrict__ bi2, const float* __restrict__ bh2,
    const float* __restrict__ bi3, const float* __restrict__ bh3,
    float* __restrict__ bias, unsigned int* __restrict__ hbuf_u,
    unsigned int* __restrict__ flags)
{
    int idx = blockIdx.x * 256 + threadIdx.x;   // grid 256x256 = 65536
    hbuf_u[idx] = 0u;                            // 65536 u32 = 262144 B (both phases)
    if (idx < 4096) {
        int g = idx >> 10, j = idx & 1023;
        const float* bi = (g == 0) ? bi0 : (g == 1) ? bi1 : (g == 2) ? bi2 : bi3;
        const float* bh = (g == 0) ? bh0 : (g == 1) ? bh1 : (g == 2) ? bh2 : bh3;
        bias[idx] = bi[j] + bh[j];
    }
    if (idx < 256) flags[idx] = 0u;              // 8 groups x 32 WG epoch flags
}

// ---------------------------------------------------------------------------
// x_proj GEMM: x[32768][1024] @ Wi[1024][4096] -> xp[b*512+t][h][gate] bf16
// (gate-interleaved so the scan reads 4 gates with one 8B load).
__global__ __launch_bounds__(256, 2) void gemm_xproj(
    const float* __restrict__ x, const unsigned short* __restrict__ wiT,
    unsigned short* __restrict__ xp)
{
    __shared__ unsigned short sA[128 * 72];   // [m][k], stride 72 bf16 (pad 16B)
    __shared__ unsigned short sB[128 * 72];   // [n][k] (WiT already n-major)
    int bid = blockIdx.x;
    int mt = bid >> 5, nt = bid & 31;
    long m0 = (long)mt * 128;
    int n0 = nt * 128;
    int tid = threadIdx.x;
    int lane = tid & 63, wv = tid >> 6;
    int quad = lane >> 4, l15 = lane & 15;
    int wm = wv & 1, wn = wv >> 1;

    f32x4 acc[4][4];
    #pragma unroll
    for (int a = 0; a < 4; a++)
        #pragma unroll
        for (int b = 0; b < 4; b++)
            acc[a][b] = (f32x4){0.f, 0.f, 0.f, 0.f};

    for (int kb = 0; kb < 16; kb++) {
        int k0 = kb * 64;
        #pragma unroll
        for (int i = 0; i < 8; i++) {
            int ch = tid + i * 256;
            int row = ch >> 4, q = ch & 15;
            float4 v = *(const float4*)&x[(m0 + row) * 1024 + k0 + q * 4];
            uint2 p;
            p.x = (unsigned int)f2bf(v.x) | ((unsigned int)f2bf(v.y) << 16);
            p.y = (unsigned int)f2bf(v.z) | ((unsigned int)f2bf(v.w) << 16);
            *(uint2*)&sA[row * 72 + q * 4] = p;
        }
        #pragma unroll
        for (int i = 0; i < 4; i++) {
            int ch = tid + i * 256;
            int row = ch >> 3, q = ch & 7;
            uint4 v = *(const uint4*)&wiT[(long)(n0 + row) * 1024 + k0 + q * 8];
            *(uint4*)&sB[row * 72 + q * 8] = v;
        }
        __syncthreads();
        #pragma unroll
        for (int ks = 0; ks < 2; ks++) {
            bf16x8 af[4], bfr[4];
            #pragma unroll
            for (int mi2 = 0; mi2 < 4; mi2++)
                af[mi2] = *(const bf16x8*)&sA[(wm * 64 + mi2 * 16 + l15) * 72 + ks * 32 + quad * 8];
            #pragma unroll
            for (int ni = 0; ni < 4; ni++)
                bfr[ni] = *(const bf16x8*)&sB[(wn * 64 + ni * 16 + l15) * 72 + ks * 32 + quad * 8];
            #pragma unroll
            for (int mi2 = 0; mi2 < 4; mi2++)
                #pragma unroll
                for (int ni = 0; ni < 4; ni++)
                    acc[mi2][ni] = __builtin_amdgcn_mfma_f32_16x16x32_bf16(
                        af[mi2], bfr[ni], acc[mi2][ni], 0, 0, 0);
        }
        __syncthreads();
    }
    // epilogue: C rows = quad*4+r, cols = l15; scatter by gate: xp[m][h][gate]
    #pragma unroll
    for (int mi2 = 0; mi2 < 4; mi2++)
        #pragma unroll
        for (int ni = 0; ni < 4; ni++)
            #pragma unroll
            for (int r = 0; r < 4; r++) {
                long row = m0 + wm * 64 + mi2 * 16 + quad * 4 + r;
                int col = n0 + wn * 64 + ni * 16 + l15;
                int h = col & 1023, gate = col >> 10;
                xp[row * 4096 + h * 4 + gate] = f2bf(acc[mi2][ni][r]);
            }
}

// ---------------------------------------------------------------------------
// Persistent LSTM scan. 256 blocks x 256 threads.
// group g = bid/32 (batch rows 8g..8g+7), slice s = bid%32 (h cols 32s..32s+31)
// wave w = gate w; 2 N-tiles of 16 cols -> 2 independent MFMA chains.
// A rows 8..15 of each MFMA duplicate rows 0..7 (M=8 real rows).
__global__ __launch_bounds__(256, 1) void lstm_scan(
    const unsigned short* __restrict__ xp, const unsigned short* __restrict__ whT,
    const float* __restrict__ bias, unsigned short* __restrict__ hbuf,
    unsigned int* __restrict__ flags, float* __restrict__ out)
{
    __shared__ unsigned short hl[8 * 1032];   // h tile [8][1024], stride 1032 (pad 16B)
    __shared__ float xch[4][8][32];           // gate exchange

    int bid = blockIdx.x;
    int g = bid >> 5, s = bid & 31;
    int tid = threadIdx.x;
    int lane = tid & 63, wv = tid >> 6;
    int quad = lane >> 4, l15 = lane & 15;
    int arow = l15 & 7;                       // duplicated A row

    // preload Wh fragments: B[k=kk*32+quad*8+j][n] for n = s*32 + ti*16 + l15
    bf16x8 bfrag[2][32];
    #pragma unroll
    for (int ti = 0; ti < 2; ti++) {
        const unsigned short* bp =
            whT + (long)(wv * 1024 + s * 32 + ti * 16 + l15) * 1024 + quad * 8;
        #pragma unroll
        for (int kk = 0; kk < 32; kk++)
            bfrag[ti][kk] = *(const bf16x8*)(bp + kk * 32);
    }

    int row = tid >> 5, col = tid & 31;       // elementwise ownership (8x32)
    float b4[4];
    #pragma unroll
    for (int gg = 0; gg < 4; gg++) b4[gg] = bias[gg * 1024 + s * 32 + col];

    float c = 0.f;
    const unsigned int* myflags = flags + g * 32 + (lane & 31);  // 2 lanes/flag
    unsigned int* myflag = flags + g * 32 + s;
    const char* hb0 = (const char*)(hbuf + (long)g * 8 * 1024);
    const char* hb1 = (const char*)(hbuf + 65536 + (long)g * 8 * 1024);
    unsigned short* hw0 = hbuf + (long)g * 8 * 1024;
    unsigned short* hw1 = hbuf + 65536 + (long)g * 8 * 1024;

    for (int t = 0; t < 512; t++) {
        // x_proj prefetch: one 8B load = all 4 gates for (batch,col). Issued
        // before the poll so its latency hides behind the wait.
        const unsigned short* xr = xp + ((long)(g * 8 + row) * 512 + t) * 4096
                                      + (s * 32 + col) * 4;
        uint2 xg = *(const uint2*)xr;
        float xpi = bf2f((unsigned short)(xg.x & 0xFFFF));
        float xpf = bf2f((unsigned short)(xg.x >> 16));
        float xpg = bf2f((unsigned short)(xg.y & 0xFFFF));
        float xpo = bf2f((unsigned short)(xg.y >> 16));

        // wait for all 32 producer WGs of this group to publish h(t)
        if (t > 0) {
            while (true) {
                unsigned int f = __hip_atomic_load(myflags, __ATOMIC_RELAXED,
                                                   __HIP_MEMORY_SCOPE_AGENT);
                if (__all((int)(f >= (unsigned int)t))) break;
                __builtin_amdgcn_s_sleep(1);
            }
        }

        // stage h(t) 16KB -> LDS via 16B cache-bypassing loads (4 per thread)
        const char* hsrc = (t & 1) ? hb1 : hb0;
        uint4v hv[4];
        #pragma unroll
        for (int i = 0; i < 4; i++) {
            int ch = tid + i * 256;                // 1024 chunks of 16B
            int r2 = ch >> 7, off = ch & 127;
            const void* p = hsrc + r2 * 2048 + off * 16;
            asm volatile("global_load_dwordx4 %0, %1, off sc0 sc1"
                         : "=v"(hv[i]) : "v"(p) : "memory");
        }
        asm volatile("s_waitcnt vmcnt(0)" ::: "memory");
        #pragma unroll
        for (int i = 0; i < 4; i++) {
            int ch = tid + i * 256;
            int r2 = ch >> 7, off = ch & 127;
            *(uint4v*)&hl[r2 * 1032 + off * 8] = hv[i];
        }
        __syncthreads();

        // gate tile for this wave: 8x32 over K=1024, 2 independent chains
        f32x4 acc0 = {0.f, 0.f, 0.f, 0.f};
        f32x4 acc1 = {0.f, 0.f, 0.f, 0.f};
        #pragma unroll
        for (int kk = 0; kk < 32; kk++) {
            bf16x8 af = *(const bf16x8*)&hl[arow * 1032 + kk * 32 + quad * 8];
            acc0 = __builtin_amdgcn_mfma_f32_16x16x32_bf16(af, bfrag[0][kk], acc0, 0, 0, 0);
            acc1 = __builtin_amdgcn_mfma_f32_16x16x32_bf16(af, bfrag[1][kk], acc1, 0, 0, 0);
        }
        if (quad < 2) {                         // C rows 0..7 are the real rows
            #pragma unroll
            for (int r = 0; r < 4; r++) {
                xch[wv][quad * 4 + r][l15] = acc0[r];
                xch[wv][quad * 4 + r][16 + l15] = acc1[r];
            }
        }
        __syncthreads();

        // elementwise LSTM cell
        float gi = xch[0][row][col] + xpi + b4[0];
        float gf = xch[1][row][col] + xpf + b4[1];
        float gg_ = xch[2][row][col] + xpg + b4[2];
        float go = xch[3][row][col] + xpo + b4[3];
        float iv = 1.f / (1.f + __expf(-gi));
        float fv = 1.f / (1.f + __expf(-gf));
        float gv = 1.f - 2.f / (__expf(2.f * gg_) + 1.f);   // tanh
        float ov = 1.f / (1.f + __expf(-go));
        c = c * fv + iv * gv;
        float h = ov * (1.f - 2.f / (__expf(2.f * c) + 1.f));

        if (t == 511) {
            out[(g * 8 + row) * 1024 + s * 32 + col] = h;
            out[65536 + (g * 8 + row) * 1024 + s * 32 + col] = c;
        } else {
            // publish h slice write-through (visible at MALL once retired)
            unsigned short* hdst = (t & 1) ? hw0 : hw1;
            __hip_atomic_store(&hdst[row * 1024 + s * 32 + col], f2bf(h),
                               __ATOMIC_RELAXED, __HIP_MEMORY_SCOPE_AGENT);
            // __syncthreads: each wave drains vmcnt(0) before s_barrier, so after
            // the barrier ALL h stores of this WG are at the coherence point.
            __syncthreads();
            if (tid == 0)
                __hip_atomic_store(myflag, (unsigned int)(t + 1),
                                   __ATOMIC_RELAXED, __HIP_MEMORY_SCOPE_AGENT);
            // no trailing barrier: next-iter poll is per-wave.
        }
    }
}

// ---------------------------------------------------------------------------
extern "C" void kernel_launch(void* const* d_in, const int* in_sizes, int n_in,
                              void* d_out, int out_size, void* d_ws, size_t ws_size,
                              hipStream_t stream)
{
    const float* x    = (const float*)d_in[0];
    const float* w_ii = (const float*)d_in[1];
    const float* b_ii = (const float*)d_in[2];
    const float* w_hi = (const float*)d_in[3];
    const float* b_hi = (const float*)d_in[4];
    const float* w_if = (const float*)d_in[5];
    const float* b_if = (const float*)d_in[6];
    const float* w_hf = (const float*)d_in[7];
    const float* b_hf = (const float*)d_in[8];
    const float* w_ig = (const float*)d_in[9];
    const float* b_ig = (const float*)d_in[10];
    const float* w_hg = (const float*)d_in[11];
    const float* b_hg = (const float*)d_in[12];
    const float* w_io = (const float*)d_in[13];
    const float* b_io = (const float*)d_in[14];
    const float* w_ho = (const float*)d_in[15];
    const float* b_ho = (const float*)d_in[16];

    // Workspace layout. Total = 285,493,248 B.
    const size_t OFF_XPJ  = 0;                       // 268,435,456 B
    const size_t OFF_WIT  = 268435456;               //   8,388,608 B
    const size_t OFF_WHT  = 276824064;               //   8,388,608 B
    const size_t OFF_BIAS = 285212672;               //      16,384 B
    const size_t OFF_HBUF = 285229056;               //     262,144 B
    const size_t OFF_FLG  = 285491200;               //       2,048 B
    const size_t NEEDED   = 285493248;
    if (ws_size < NEEDED) return;

    char* ws = (char*)d_ws;
    unsigned short* xpj      = (unsigned short*)(ws + OFF_XPJ);
    unsigned short* wiT      = (unsigned short*)(ws + OFF_WIT);
    unsigned short* whT      = (unsigned short*)(ws + OFF_WHT);
    float*          bias     = (float*)(ws + OFF_BIAS);
    unsigned short* hbuf     = (unsigned short*)(ws + OFF_HBUF);
    unsigned int*   flags    = (unsigned int*)(ws + OFF_FLG);

    pack_wT<<<2048, 256, 0, stream>>>(w_ii, w_if, w_ig, w_io,
                                      w_hi, w_hf, w_hg, w_ho, wiT, whT);
    pack_misc<<<256, 256, 0, stream>>>(b_ii, b_hi, b_if, b_hf, b_ig, b_hg, b_io, b_ho,
                                       bias, (unsigned int*)hbuf, flags);
    gemm_xproj<<<8192, 256, 0, stream>>>(x, wiT, xpj);
    lstm_scan<<<256, 256, 0, stream>>>(xpj, whT, bias, hbuf, flags, (float*)d_out);
}